// Round 1
// baseline (256.870 us; speedup 1.0000x reference)
//
#include <hip/hip_runtime.h>
#include <hip/hip_bf16.h>
#include <math.h>

#define OBS_X 40.0f
#define OBS_Y 15.0f
#define RADIUS 6.0f

__global__ __launch_bounds__(256) void barriernet_kernel(
    const float* __restrict__ x,
    const float* __restrict__ mean_, const float* __restrict__ std_,
    const float* __restrict__ w1,  const float* __restrict__ b1,
    const float* __restrict__ w21, const float* __restrict__ b21,
    const float* __restrict__ w22, const float* __restrict__ b22,
    const float* __restrict__ w31, const float* __restrict__ b31,
    const float* __restrict__ w32, const float* __restrict__ b32,
    float* __restrict__ out, int n)
{
    int i = blockIdx.x * blockDim.x + threadIdx.x;
    if (i >= n) return;

    // ---- load row (5 floats, contiguous per thread) ----
    const float* xr = x + (size_t)i * 5;
    float xv[5];
#pragma unroll
    for (int k = 0; k < 5; ++k) xv[k] = xr[k];

    // ---- fc1: 5 -> 128, relu. h1 kept entirely in VGPRs (const indices). ----
    float h1[128];
#pragma unroll
    for (int j = 0; j < 128; ++j) {
        float a = b1[j];
#pragma unroll
        for (int k = 0; k < 5; ++k) a = fmaf(xv[k], w1[j * 5 + k], a);
        h1[j] = fmaxf(a, 0.0f);
    }

    // ---- fc21 (128->32, relu) folded directly into fc31 head (32->2) ----
    float a31_0 = b31[0], a31_1 = b31[1];
#pragma unroll 4
    for (int j = 0; j < 32; ++j) {
        float a = b21[j];
        const float* wr = w21 + j * 128;
#pragma unroll
        for (int k = 0; k < 128; ++k) a = fmaf(h1[k], wr[k], a);
        a = fmaxf(a, 0.0f);
        a31_0 = fmaf(w31[j],      a, a31_0);
        a31_1 = fmaf(w31[32 + j], a, a31_1);
    }

    // ---- fc22 (128->32, relu) folded directly into fc32 head (32->2) ----
    float a32_0 = b32[0], a32_1 = b32[1];
#pragma unroll 4
    for (int j = 0; j < 32; ++j) {
        float a = b22[j];
        const float* wr = w22 + j * 128;
#pragma unroll
        for (int k = 0; k < 128; ++k) a = fmaf(h1[k], wr[k], a);
        a = fmaxf(a, 0.0f);
        a32_0 = fmaf(w32[j],      a, a32_0);
        a32_1 = fmaf(w32[32 + j], a, a32_1);
    }

    // x32 = 4 * sigmoid(head)
    float s0 = 4.0f / (1.0f + __expf(-a32_0));
    float s1 = 4.0f / (1.0f + __expf(-a32_1));

    // ---- physics epilogue (uses x0 = x*std + mean, components 0..3) ----
    float px = fmaf(xv[0], std_[0], mean_[0]);
    float py = fmaf(xv[1], std_[1], mean_[1]);
    float th = fmaf(xv[2], std_[2], mean_[2]);
    float v  = fmaf(xv[3], std_[3], mean_[3]);

    float sn, cs;
    __sincosf(th, &sn, &cs);

    float dx = px - OBS_X, dy = py - OBS_Y;
    float barrier     = dx * dx + dy * dy - RADIUS * RADIUS;
    float barrier_dot = 2.0f * dx * v * cs + 2.0f * dy * v * sn;
    float Lf2b        = 2.0f * v * v;
    float LgLfbu1     = -2.0f * dx * v * sn + 2.0f * dy * v * cs;
    float LgLfbu2     =  2.0f * dx * cs + 2.0f * dy * sn;
    float G0 = -LgLfbu1, G1 = -LgLfbu2;

    float h   = Lf2b + (s0 + s1) * barrier_dot + s0 * s1 * barrier;
    float u00 = -a31_0, u01 = -a31_1;
    float viol = G0 * u00 + G1 * u01 - h;
    float gg   = G0 * G0 + G1 * G1;
    float lam  = fmaxf(viol, 0.0f) / (gg + 1e-12f);

    float2 uo = make_float2(fmaf(-lam, G0, u00), fmaf(-lam, G1, u01));
    reinterpret_cast<float2*>(out)[i] = uo;
}

extern "C" void kernel_launch(void* const* d_in, const int* in_sizes, int n_in,
                              void* d_out, int out_size, void* d_ws, size_t ws_size,
                              hipStream_t stream) {
    const float* x     = (const float*)d_in[0];
    // d_in[1] = sgn (unused by the reference computation)
    const float* mean_ = (const float*)d_in[2];
    const float* std_  = (const float*)d_in[3];
    const float* w1    = (const float*)d_in[4];
    const float* b1    = (const float*)d_in[5];
    const float* w21   = (const float*)d_in[6];
    const float* b21   = (const float*)d_in[7];
    const float* w22   = (const float*)d_in[8];
    const float* b22   = (const float*)d_in[9];
    const float* w31   = (const float*)d_in[10];
    const float* b31   = (const float*)d_in[11];
    const float* w32   = (const float*)d_in[12];
    const float* b32   = (const float*)d_in[13];

    int n = in_sizes[0] / 5;
    int block = 256;
    int grid = (n + block - 1) / block;

    barriernet_kernel<<<grid, block, 0, stream>>>(
        x, mean_, std_, w1, b1, w21, b21, w22, b22, w31, b31, w32, b32,
        (float*)d_out, n);
}

// Round 3
// 154.497 us; speedup vs baseline: 1.6626x; 1.6626x over previous
//
#include <hip/hip_runtime.h>
#include <hip/hip_bf16.h>
#include <math.h>

typedef __attribute__((ext_vector_type(8))) _Float16 half8;  // 8 x f16 (4 VGPR)
typedef __attribute__((ext_vector_type(4))) float f32x4;     // MFMA acc

#define OBS_X 40.0f
#define OBS_Y 15.0f
#define RADIUS 6.0f

__device__ __forceinline__ unsigned short f16hi(float v) {
    _Float16 h = (_Float16)v;
    return __builtin_bit_cast(unsigned short, h);
}
__device__ __forceinline__ float f16f(unsigned short b) {
    return (float)__builtin_bit_cast(_Float16, b);
}

// ws layout (ushort units):
//   [0,8192)      w2hi frags: [(t*4+kc)*64 + lane]*8 + j   (w2cat = [w21;w22], 64 cols)
//   [8192,16384)  w2lo frags
//   [16384,17408) w1hi frags: [fr]*8 + j  (K-padded 5->8; k>=8 handled as zero lanes)
//   [17408,18432) w1lo frags
__global__ void prep_kernel(const float* __restrict__ w1,
                            const float* __restrict__ w21,
                            const float* __restrict__ w22,
                            unsigned short* __restrict__ ws) {
    int tid = blockIdx.x * blockDim.x + threadIdx.x;    // 16*256 = 4096 threads
#pragma unroll
    for (int m = 0; m < 2; ++m) {
        int idx = tid * 2 + m;                          // 0..8191
        int j = idx & 7, l = (idx >> 3) & 63, kc = (idx >> 9) & 3, t = idx >> 11;
        int c = t * 16 + (l & 15);                      // output col 0..63
        int k = kc * 32 + (l >> 4) * 8 + j;             // k 0..127
        float v = (c < 32) ? w21[c * 128 + k] : w22[(c - 32) * 128 + k];
        _Float16 h  = (_Float16)v;
        _Float16 lo = (_Float16)(v - (float)h);
        ws[idx]        = __builtin_bit_cast(unsigned short, h);
        ws[8192 + idx] = __builtin_bit_cast(unsigned short, lo);
    }
    if (tid < 1024) {
        int j = tid & 7, fr = tid >> 3;                 // fr = feature row 0..127
        float v = (j < 5) ? w1[fr * 5 + j] : 0.0f;      // K-pad with zeros
        _Float16 h  = (_Float16)v;
        _Float16 lo = (_Float16)(v - (float)h);
        ws[16384 + tid] = __builtin_bit_cast(unsigned short, h);
        ws[17408 + tid] = __builtin_bit_cast(unsigned short, lo);
    }
}

// 4-product fp16 split GEMM step: (ah+al)(bh+bl), smallest terms first
#define MFMA4(acc, ah_, al_, bh_, bl_)                                      \
    acc = __builtin_amdgcn_mfma_f32_16x16x32_f16(al_, bl_, acc, 0, 0, 0);   \
    acc = __builtin_amdgcn_mfma_f32_16x16x32_f16(al_, bh_, acc, 0, 0, 0);   \
    acc = __builtin_amdgcn_mfma_f32_16x16x32_f16(ah_, bl_, acc, 0, 0, 0);   \
    acc = __builtin_amdgcn_mfma_f32_16x16x32_f16(ah_, bh_, acc, 0, 0, 0);

__global__ __launch_bounds__(256, 4) void barriernet_mfma(
    const float* __restrict__ x,
    const float* __restrict__ mean_, const float* __restrict__ std_,
    const float* __restrict__ b1,
    const float* __restrict__ b21, const float* __restrict__ b22,
    const float* __restrict__ w31, const float* __restrict__ b31,
    const float* __restrict__ w32, const float* __restrict__ b32,
    const unsigned short* __restrict__ ws,
    float* __restrict__ out)
{
    // Per-wave h1 planes (XOR-swizzled). No cross-wave sharing -> no barriers.
    __shared__ unsigned char smem[4 * 8192];            // 32768 B -> 4 blocks/CU
    const int tid  = threadIdx.x;
    const int lane = tid & 63;
    const int wv   = tid >> 6;
    const int r16  = lane & 15;      // batch row (as MFMA col) within the wave's 16-row tile
    const int g    = lane >> 4;      // lane group 0..3
    unsigned char* h1hi = smem + wv * 8192;             // [16 rows][128 feats] f16, 256B rows
    unsigned char* h1lo = h1hi + 4096;

    const int rowbase = blockIdx.x * 64 + wv * 16;
    const unsigned swz = ((unsigned)(r16 & 7)) << 4;    // bank-conflict XOR swizzle

    // ---- phase 1: x load + B-frag (x^T) build. lanes 0-15 own rows; k>=8 lanes are zero pad ----
    float xv0 = 0.f, xv1 = 0.f, xv2 = 0.f, xv3 = 0.f;
    half8 bxh = {0,0,0,0,0,0,0,0}, bxl = {0,0,0,0,0,0,0,0};
    if (lane < 16) {
        const float* xr = x + (size_t)(rowbase + r16) * 5;
        float v4;
        xv0 = xr[0]; xv1 = xr[1]; xv2 = xr[2]; xv3 = xr[3]; v4 = xr[4];
        _Float16 h;
        h = (_Float16)xv0; bxh[0] = h; bxl[0] = (_Float16)(xv0 - (float)h);
        h = (_Float16)xv1; bxh[1] = h; bxl[1] = (_Float16)(xv1 - (float)h);
        h = (_Float16)xv2; bxh[2] = h; bxl[2] = (_Float16)(xv2 - (float)h);
        h = (_Float16)xv3; bxh[3] = h; bxl[3] = (_Float16)(xv3 - (float)h);
        h = (_Float16)v4;  bxh[4] = h; bxl[4] = (_Float16)(v4  - (float)h);
    }

    // ---- phase 2: fc1 = relu(W1 x^T + b1), swapped orientation D'[feat][batch] ----
    // D' lane map: batch col = r16, feats = 16t + 4g + r  -> pack 4 consecutive feats, b64 LDS write
#pragma unroll
    for (int t = 0; t < 8; ++t) {
        half8 awh = {0,0,0,0,0,0,0,0}, awl = {0,0,0,0,0,0,0,0};
        if (lane < 16) {
            awh = *(const half8*)(ws + 16384 + (t * 16 + lane) * 8);
            awl = *(const half8*)(ws + 17408 + (t * 16 + lane) * 8);
        }
        const float4 bb = *(const float4*)(b1 + t * 16 + g * 4);
        f32x4 acc = {bb.x, bb.y, bb.z, bb.w};
        MFMA4(acc, awh, awl, bxh, bxl);
        float v0 = fmaxf(acc[0], 0.f), v1 = fmaxf(acc[1], 0.f);
        float v2 = fmaxf(acc[2], 0.f), v3 = fmaxf(acc[3], 0.f);
        unsigned short h0 = f16hi(v0), h1v = f16hi(v1), h2 = f16hi(v2), h3 = f16hi(v3);
        unsigned short l0 = f16hi(v0 - f16f(h0)), l1 = f16hi(v1 - f16f(h1v));
        unsigned short l2 = f16hi(v2 - f16f(h2)), l3 = f16hi(v3 - f16f(h3));
        const unsigned off = ((unsigned)(32 * t + 8 * g)) ^ swz;
        uint2 ph; ph.x = (unsigned)h0 | ((unsigned)h1v << 16); ph.y = (unsigned)h2 | ((unsigned)h3 << 16);
        uint2 pl; pl.x = (unsigned)l0 | ((unsigned)l1  << 16); pl.y = (unsigned)l2 | ((unsigned)l3 << 16);
        *(uint2*)(h1hi + r16 * 256 + off) = ph;
        *(uint2*)(h1lo + r16 * 256 + off) = pl;
    }

    // ---- phase 3: fc2cat = [fc21;fc22] : 16x64 = (16x128)@(128x64), fp16x4 ----
    half8 ah[4], al[4];
#pragma unroll
    for (int kc = 0; kc < 4; ++kc) {
        const unsigned off = ((unsigned)(kc * 64 + g * 16)) ^ swz;
        ah[kc] = *(const half8*)(h1hi + r16 * 256 + off);
        al[kc] = *(const half8*)(h1lo + r16 * 256 + off);
    }
    f32x4 acc2[4];
#pragma unroll
    for (int t = 0; t < 4; ++t) {
        const float bias = (t < 2) ? b21[t * 16 + r16] : b22[(t - 2) * 16 + r16];
        f32x4 a = {bias, bias, bias, bias};
#pragma unroll
        for (int kc = 0; kc < 4; ++kc) {
            const half8 bh = *(const half8*)(ws + ((t * 4 + kc) * 64 + lane) * 8);
            const half8 bl = *(const half8*)(ws + 8192 + ((t * 4 + kc) * 64 + lane) * 8);
            MFMA4(a, ah[kc], al[kc], bh, bl);
        }
        acc2[t] = a;
    }

    // ---- phase 4: heads. lane holds batch rows {4g+r}, col c = 16t + r16; butterfly over r16,
    //      then shuffle-gather the 4 head values to the owning lane (batch b -> lane b, b<16) ----
    const float w310a = w31[r16],      w310b = w31[16 + r16];
    const float w311a = w31[32 + r16], w311b = w31[48 + r16];
    const float w320a = w32[r16],      w320b = w32[16 + r16];
    const float w321a = w32[32 + r16], w321b = w32[48 + r16];
    float A0 = 0.f, A1 = 0.f, A2 = 0.f, A3 = 0.f;       // valid on lanes<16 after the loop
    const int src = (lane >> 2) << 4;                   // (b>>2)*16 for reading lane b
#pragma unroll
    for (int r = 0; r < 4; ++r) {
        float v0 = fmaxf(acc2[0][r], 0.f), v1 = fmaxf(acc2[1][r], 0.f);
        float v2 = fmaxf(acc2[2][r], 0.f), v3 = fmaxf(acc2[3][r], 0.f);
        float p0 = v0 * w310a + v1 * w310b;
        float p1 = v0 * w311a + v1 * w311b;
        float p2 = v2 * w320a + v3 * w320b;
        float p3 = v2 * w321a + v3 * w321b;
#pragma unroll
        for (int d = 1; d <= 8; d <<= 1) {              // butterfly over the 16-lane col dim
            p0 += __shfl_xor(p0, d);
            p1 += __shfl_xor(p1, d);
            p2 += __shfl_xor(p2, d);
            p3 += __shfl_xor(p3, d);
        }
        float q0 = __shfl(p0, src), q1 = __shfl(p1, src);
        float q2 = __shfl(p2, src), q3 = __shfl(p3, src);
        if ((lane & 3) == r) { A0 = q0; A1 = q1; A2 = q2; A3 = q3; }
    }

    // ---- phase 5: physics epilogue, lanes 0-15 reuse x registers from phase 1 ----
    if (lane < 16) {
        const float a31_0 = A0 + b31[0], a31_1 = A1 + b31[1];
        const float a32_0 = A2 + b32[0], a32_1 = A3 + b32[1];
        const float s0 = 4.0f / (1.0f + __expf(-a32_0));
        const float s1 = 4.0f / (1.0f + __expf(-a32_1));
        const float px = fmaf(xv0, std_[0], mean_[0]);
        const float py = fmaf(xv1, std_[1], mean_[1]);
        const float th = fmaf(xv2, std_[2], mean_[2]);
        const float v  = fmaf(xv3, std_[3], mean_[3]);
        float sn, cs; __sincosf(th, &sn, &cs);
        const float dx = px - OBS_X, dy = py - OBS_Y;
        const float barrier     = dx * dx + dy * dy - RADIUS * RADIUS;
        const float barrier_dot = 2.f * dx * v * cs + 2.f * dy * v * sn;
        const float Lf2b = 2.f * v * v;
        const float G0 = 2.f * dx * v * sn - 2.f * dy * v * cs;   // -LgLfbu1
        const float G1 = -(2.f * dx * cs + 2.f * dy * sn);        // -LgLfbu2
        const float h  = Lf2b + (s0 + s1) * barrier_dot + s0 * s1 * barrier;
        const float u00 = -a31_0, u01 = -a31_1;
        const float viol = G0 * u00 + G1 * u01 - h;
        const float gg   = G0 * G0 + G1 * G1;
        const float lam  = fmaxf(viol, 0.f) / (gg + 1e-12f);
        float2 uo = make_float2(fmaf(-lam, G0, u00), fmaf(-lam, G1, u01));
        ((float2*)out)[rowbase + lane] = uo;
    }
}

extern "C" void kernel_launch(void* const* d_in, const int* in_sizes, int n_in,
                              void* d_out, int out_size, void* d_ws, size_t ws_size,
                              hipStream_t stream) {
    const float* x     = (const float*)d_in[0];
    // d_in[1] = sgn (unused by the reference computation)
    const float* mean_ = (const float*)d_in[2];
    const float* std_  = (const float*)d_in[3];
    const float* w1    = (const float*)d_in[4];
    const float* b1    = (const float*)d_in[5];
    const float* w21   = (const float*)d_in[6];
    const float* b21   = (const float*)d_in[7];
    const float* w22   = (const float*)d_in[8];
    const float* b22   = (const float*)d_in[9];
    const float* w31   = (const float*)d_in[10];
    const float* b31   = (const float*)d_in[11];
    const float* w32   = (const float*)d_in[12];
    const float* b32   = (const float*)d_in[13];
    unsigned short* ws = (unsigned short*)d_ws;

    const int n = in_sizes[0] / 5;              // 524288 rows
    prep_kernel<<<16, 256, 0, stream>>>(w1, w21, w22, ws);
    barriernet_mfma<<<n / 64, 256, 0, stream>>>(
        x, mean_, std_, b1, b21, b22, w31, b31, w32, b32, ws, (float*)d_out);
}

// Round 6
// 146.115 us; speedup vs baseline: 1.7580x; 1.0574x over previous
//
#include <hip/hip_runtime.h>
#include <hip/hip_bf16.h>
#include <math.h>

typedef __attribute__((ext_vector_type(8))) _Float16 half8;   // 8 x f16 (4 VGPR)
typedef __attribute__((ext_vector_type(2))) _Float16 half2v;
typedef __attribute__((ext_vector_type(4))) float f32x4;      // MFMA acc

#define OBS_X 40.0f
#define OBS_Y 15.0f
#define RADIUS 6.0f
#define TPW 8       // tiles (16 rows each) per wave
#define GRID 1024   // 1024 blocks * 4 waves * TPW * 16 rows = 524288

__device__ __forceinline__ half2v pkrtz(float a, float b) {
    return __builtin_bit_cast(half2v, __builtin_amdgcn_cvt_pkrtz(a, b));
}

// fp16 hi/lo split of 8 floats (RNE casts)
__device__ __forceinline__ void split8(const float* v, half8& hi, half8& lo) {
#pragma unroll
    for (int j = 0; j < 8; ++j) {
        _Float16 h = (_Float16)v[j];
        hi[j] = h;
        lo[j] = (_Float16)(v[j] - (float)h);
    }
}

__global__ __launch_bounds__(256, 2) void barriernet_fused(
    const float* __restrict__ x,
    const float* __restrict__ mean_, const float* __restrict__ std_,
    const float* __restrict__ w1,  const float* __restrict__ b1,
    const float* __restrict__ w21, const float* __restrict__ b21,
    const float* __restrict__ w22, const float* __restrict__ b22,
    const float* __restrict__ w31, const float* __restrict__ b31,
    const float* __restrict__ w32, const float* __restrict__ b32,
    float* __restrict__ out)
{
    // smem: [0,32768) 4 per-wave h1 hi/lo planes (XOR-swizzled, no cross-wave use)
    //       [32768,36864) w1' frag-ready hi/lo (w1 cols 0-4, b1 in col 5, 0-pad)
    __shared__ unsigned char smem[36864];
    const int tid  = threadIdx.x;
    const int lane = tid & 63;
    const int wv   = tid >> 6;
    const int r16  = lane & 15;     // batch row within tile / MFMA col
    const int g    = lane >> 4;     // lane group 0..3 (k-slice / D-row group)
    unsigned char* h1hi = smem + wv * 8192;             // [16 rows][128 feats] f16, 256B rows
    unsigned char* h1lo = h1hi + 4096;
    unsigned short* w1h_lds = (unsigned short*)(smem + 32768);  // [128 fr][8 j]
    unsigned short* w1l_lds = w1h_lds + 1024;
    const unsigned swz = ((unsigned)(r16 & 7)) << 4;
    const int slot = blockIdx.x * 4 + wv;               // 0..4095

    // ---- one-time: build w1' frags in LDS (threads 0-127: one feature row each) ----
    if (tid < 128) {
        float v[8];
#pragma unroll
        for (int j = 0; j < 5; ++j) v[j] = w1[tid * 5 + j];
        v[5] = b1[tid];                                 // bias as K-column 5 (x slot 5 = 1.0)
        v[6] = 0.f; v[7] = 0.f;
        half8 hi, lo;
        split8(v, hi, lo);
        *(half8*)(w1h_lds + tid * 8) = hi;
        *(half8*)(w1l_lds + tid * 8) = lo;
    }

    // ---- one-time: gather w2cat fragments into registers (128 VGPR) ----
    // frag lane l holds A[row=l&15][k=(l>>4)*8+j]; tile t covers w2cat rows 16t..16t+15
    half8 w2h[4][4], w2l[4][4];
#pragma unroll
    for (int t = 0; t < 4; ++t) {
        const int r = 16 * t + r16;
        const float* src = (r < 32) ? (w21 + r * 128) : (w22 + (r - 32) * 128);
#pragma unroll
        for (int kc = 0; kc < 4; ++kc) {
            const float4 f0 = *(const float4*)(src + kc * 32 + g * 8);
            const float4 f1 = *(const float4*)(src + kc * 32 + g * 8 + 4);
            float v[8];
            v[0] = f0.x; v[1] = f0.y; v[2] = f0.z; v[3] = f0.w;
            v[4] = f1.x; v[5] = f1.y; v[6] = f1.z; v[7] = f1.w;
            split8(v, w2h[t][kc], w2l[t][kc]);
        }
    }

    __syncthreads();    // w1' LDS ready; only barrier in the kernel

    // hoisted uniform scalars (SGPR)
    const float m0 = mean_[0], m1 = mean_[1], m2 = mean_[2], m3 = mean_[3];
    const float sd0 = std_[0], sd1 = std_[1], sd2 = std_[2], sd3 = std_[3];
    const float bb31_0 = b31[0], bb31_1 = b31[1], bb32_0 = b32[0], bb32_1 = b32[1];

    half8 bxh = {0,0,0,0,0,0,0,0}, bxl = {0,0,0,0,0,0,0,0};
    if (lane < 16) bxh[5] = (_Float16)1.0f;             // bias column multiplier

    // ---- x prefetch for tile 0 (lanes 0-15 own rows) ----
    float xa0 = 0.f, xa1 = 0.f, xa2 = 0.f, xa3 = 0.f, xa4 = 0.f;
    if (lane < 16) {
        const float* xr = x + (size_t)(slot * TPW * 16 + r16) * 5;
        xa0 = xr[0]; xa1 = xr[1]; xa2 = xr[2]; xa3 = xr[3]; xa4 = xr[4];
    }

#pragma unroll 1
    for (int it = 0; it < TPW; ++it) {
        const int rowbase = (slot * TPW + it) * 16;

        // split current x into the fc1 B-frag (x^T; lanes>=16 stay zero = K-pad)
        if (lane < 16) {
            _Float16 h;
            h = (_Float16)xa0; bxh[0] = h; bxl[0] = (_Float16)(xa0 - (float)h);
            h = (_Float16)xa1; bxh[1] = h; bxl[1] = (_Float16)(xa1 - (float)h);
            h = (_Float16)xa2; bxh[2] = h; bxl[2] = (_Float16)(xa2 - (float)h);
            h = (_Float16)xa3; bxh[3] = h; bxl[3] = (_Float16)(xa3 - (float)h);
            h = (_Float16)xa4; bxh[4] = h; bxl[4] = (_Float16)(xa4 - (float)h);
        }
        const float xc0 = xa0, xc1 = xa1, xc2 = xa2, xc3 = xa3;  // for epilogue

        // prefetch next tile's x (latency hides under fc1/fc2)
        if (it + 1 < TPW && lane < 16) {
            const float* xr = x + (size_t)(rowbase + 16 + r16) * 5;
            xa0 = xr[0]; xa1 = xr[1]; xa2 = xr[2]; xa3 = xr[3]; xa4 = xr[4];
        }

        // ---- fc1 = relu(W1' [x;1]^T), D'[feat 16t8+4g+r][batch r16], fp16x3 ----
#pragma unroll
        for (int t8 = 0; t8 < 8; ++t8) {
            half8 awh = {0,0,0,0,0,0,0,0}, awl = {0,0,0,0,0,0,0,0};
            if (lane < 16) {
                awh = *(const half8*)(w1h_lds + (t8 * 16 + r16) * 8);
                awl = *(const half8*)(w1l_lds + (t8 * 16 + r16) * 8);
            }
            f32x4 acc = {0.f, 0.f, 0.f, 0.f};
            acc = __builtin_amdgcn_mfma_f32_16x16x32_f16(awh, bxl, acc, 0, 0, 0);
            acc = __builtin_amdgcn_mfma_f32_16x16x32_f16(awl, bxh, acc, 0, 0, 0);
            acc = __builtin_amdgcn_mfma_f32_16x16x32_f16(awh, bxh, acc, 0, 0, 0);
            float v0 = fmaxf(acc[0], 0.f), v1 = fmaxf(acc[1], 0.f);
            float v2 = fmaxf(acc[2], 0.f), v3 = fmaxf(acc[3], 0.f);
            half2v hA = pkrtz(v0, v1);
            half2v hB = pkrtz(v2, v3);
            half2v lA = pkrtz(v0 - (float)hA[0], v1 - (float)hA[1]);
            half2v lB = pkrtz(v2 - (float)hB[0], v3 - (float)hB[1]);
            const unsigned off = ((unsigned)(32 * t8 + 8 * g)) ^ swz;
            uint2 ph; ph.x = __builtin_bit_cast(unsigned, hA); ph.y = __builtin_bit_cast(unsigned, hB);
            uint2 pl; pl.x = __builtin_bit_cast(unsigned, lA); pl.y = __builtin_bit_cast(unsigned, lB);
            *(uint2*)(h1hi + r16 * 256 + off) = ph;
            *(uint2*)(h1lo + r16 * 256 + off) = pl;
        }

        asm volatile("" ::: "memory");   // forbid IR reorder of LDS write->read across type-puns

        // ---- fc2cat: D[out 16t+4g+r][batch r16] = W2cat(A,reg) @ h1(B,LDS), fp16x3 ----
        half8 ah[4], al[4];
#pragma unroll
        for (int kc = 0; kc < 4; ++kc) {
            const unsigned off = ((unsigned)(kc * 64 + g * 16)) ^ swz;
            ah[kc] = *(const half8*)(h1hi + r16 * 256 + off);
            al[kc] = *(const half8*)(h1lo + r16 * 256 + off);
        }
        f32x4 acc2[4];
#pragma unroll
        for (int t = 0; t < 4; ++t) {
            const float4 bb2 = (t < 2) ? *(const float4*)(b21 + 16 * t + 4 * g)
                                       : *(const float4*)(b22 + 16 * (t - 2) + 4 * g);
            f32x4 a = {bb2.x, bb2.y, bb2.z, bb2.w};
#pragma unroll
            for (int kc = 0; kc < 4; ++kc) {
                a = __builtin_amdgcn_mfma_f32_16x16x32_f16(w2h[t][kc], al[kc], a, 0, 0, 0);
                a = __builtin_amdgcn_mfma_f32_16x16x32_f16(w2l[t][kc], ah[kc], a, 0, 0, 0);
                a = __builtin_amdgcn_mfma_f32_16x16x32_f16(w2h[t][kc], ah[kc], a, 0, 0, 0);
            }
            acc2[t] = a;
        }

        asm volatile("" ::: "memory");   // forbid next-iter LDS writes moving above these reads

        // ---- heads: per-lane partials over outs {16t+4g+r}, reduce over g (2 shfls) ----
        const f32x4 wA0 = *(const f32x4*)(w31 + 4 * g);       // x31 row0, x21 inputs 0-15
        const f32x4 wA1 = *(const f32x4*)(w31 + 16 + 4 * g);  //           x21 inputs 16-31
        const f32x4 wB0 = *(const f32x4*)(w31 + 32 + 4 * g);  // x31 row1
        const f32x4 wB1 = *(const f32x4*)(w31 + 48 + 4 * g);
        const f32x4 wC0 = *(const f32x4*)(w32 + 4 * g);       // x32 row0
        const f32x4 wC1 = *(const f32x4*)(w32 + 16 + 4 * g);
        const f32x4 wD0 = *(const f32x4*)(w32 + 32 + 4 * g);  // x32 row1
        const f32x4 wD1 = *(const f32x4*)(w32 + 48 + 4 * g);
        float p0 = 0.f, p1 = 0.f, p2 = 0.f, p3 = 0.f;
#pragma unroll
        for (int r = 0; r < 4; ++r) {
            float v0 = fmaxf(acc2[0][r], 0.f), v1 = fmaxf(acc2[1][r], 0.f);
            float v2 = fmaxf(acc2[2][r], 0.f), v3 = fmaxf(acc2[3][r], 0.f);
            p0 += wA0[r] * v0 + wA1[r] * v1;
            p1 += wB0[r] * v0 + wB1[r] * v1;
            p2 += wC0[r] * v2 + wC1[r] * v3;
            p3 += wD0[r] * v2 + wD1[r] * v3;
        }
        p0 += __shfl_xor(p0, 16); p0 += __shfl_xor(p0, 32);
        p1 += __shfl_xor(p1, 16); p1 += __shfl_xor(p1, 32);
        p2 += __shfl_xor(p2, 16); p2 += __shfl_xor(p2, 32);
        p3 += __shfl_xor(p3, 16); p3 += __shfl_xor(p3, 32);

        // ---- physics epilogue on lanes 0-15 (batch = r16) ----
        if (lane < 16) {
            const float a31_0 = p0 + bb31_0, a31_1 = p1 + bb31_1;
            const float a32_0 = p2 + bb32_0, a32_1 = p3 + bb32_1;
            const float s0 = 4.0f / (1.0f + __expf(-a32_0));
            const float s1 = 4.0f / (1.0f + __expf(-a32_1));
            const float px = fmaf(xc0, sd0, m0);
            const float py = fmaf(xc1, sd1, m1);
            const float th = fmaf(xc2, sd2, m2);
            const float v  = fmaf(xc3, sd3, m3);
            float sn, cs; __sincosf(th, &sn, &cs);
            const float dx = px - OBS_X, dy = py - OBS_Y;
            const float barrier     = dx * dx + dy * dy - RADIUS * RADIUS;
            const float barrier_dot = 2.f * dx * v * cs + 2.f * dy * v * sn;
            const float Lf2b = 2.f * v * v;
            const float G0 = 2.f * dx * v * sn - 2.f * dy * v * cs;   // -LgLfbu1
            const float G1 = -(2.f * dx * cs + 2.f * dy * sn);        // -LgLfbu2
            const float h  = Lf2b + (s0 + s1) * barrier_dot + s0 * s1 * barrier;
            const float u00 = -a31_0, u01 = -a31_1;
            const float viol = G0 * u00 + G1 * u01 - h;
            const float gg   = G0 * G0 + G1 * G1;
            const float lam  = fmaxf(viol, 0.f) / (gg + 1e-12f);
            float2 uo = make_float2(fmaf(-lam, G0, u00), fmaf(-lam, G1, u01));
            ((float2*)out)[rowbase + r16] = uo;
        }
    }
}

extern "C" void kernel_launch(void* const* d_in, const int* in_sizes, int n_in,
                              void* d_out, int out_size, void* d_ws, size_t ws_size,
                              hipStream_t stream) {
    const float* x     = (const float*)d_in[0];
    // d_in[1] = sgn (unused by the reference computation)
    const float* mean_ = (const float*)d_in[2];
    const float* std_  = (const float*)d_in[3];
    const float* w1    = (const float*)d_in[4];
    const float* b1    = (const float*)d_in[5];
    const float* w21   = (const float*)d_in[6];
    const float* b21   = (const float*)d_in[7];
    const float* w22   = (const float*)d_in[8];
    const float* b22   = (const float*)d_in[9];
    const float* w31   = (const float*)d_in[10];
    const float* b31   = (const float*)d_in[11];
    const float* w32   = (const float*)d_in[12];
    const float* b32   = (const float*)d_in[13];

    barriernet_fused<<<GRID, 256, 0, stream>>>(
        x, mean_, std_, w1, b1, w21, b21, w22, b22, w31, b31, w32, b32,
        (float*)d_out);
}

// Round 7
// 133.647 us; speedup vs baseline: 1.9220x; 1.0933x over previous
//
#include <hip/hip_runtime.h>
#include <hip/hip_bf16.h>
#include <math.h>

typedef __attribute__((ext_vector_type(8))) _Float16 half8;   // 8 x f16 (4 VGPR)
typedef __attribute__((ext_vector_type(2))) _Float16 half2v;
typedef __attribute__((ext_vector_type(4))) float f32x4;      // MFMA acc

#define OBS_X 40.0f
#define OBS_Y 15.0f
#define RADIUS 6.0f
#define TPW 16      // tiles (16 rows each) per wave
#define GRID 512    // 512 blocks * 4 waves * TPW * 16 rows = 524288

__device__ __forceinline__ half2v pkrtz(float a, float b) {
    return __builtin_bit_cast(half2v, __builtin_amdgcn_cvt_pkrtz(a, b));
}

// fp16 hi/lo split of 8 floats (RNE casts)
__device__ __forceinline__ void split8(const float* v, half8& hi, half8& lo) {
#pragma unroll
    for (int j = 0; j < 8; ++j) {
        _Float16 h = (_Float16)v[j];
        hi[j] = h;
        lo[j] = (_Float16)(v[j] - (float)h);
    }
}

// Opaque register pin: the asm "modifies" v, so the compiler can neither
// rematerialize it from memory nor sink its producer into the loop.
__device__ __forceinline__ void pin(half8& v) {
    f32x4 t = __builtin_bit_cast(f32x4, v);
    asm volatile("" : "+v"(t));
    v = __builtin_bit_cast(half8, t);
}

__global__ __launch_bounds__(256, 2) void barriernet_fused(
    const float* __restrict__ x,
    const float* __restrict__ mean_, const float* __restrict__ std_,
    const float* __restrict__ w1,  const float* __restrict__ b1,
    const float* __restrict__ w21, const float* __restrict__ b21,
    const float* __restrict__ w22, const float* __restrict__ b22,
    const float* __restrict__ w31, const float* __restrict__ b31,
    const float* __restrict__ w32, const float* __restrict__ b32,
    float* __restrict__ out)
{
    // smem: [0,32768)      4 per-wave h1 hi/lo planes (XOR-swizzled)
    //       [32768,34816)  w1c_h [128 rows][8]: cols 0-4 = w1 hi, col 5 = b1 hi, 6-7 = 0
    //       [34816,36864)  w1c_l (lo parts)
    //       [36864,36880)  16B zero row (fc1 A-frag for lane group g==3)
    __shared__ unsigned char smem[36880];
    const int tid  = threadIdx.x;
    const int lane = tid & 63;
    const int wv   = tid >> 6;
    const int r16  = lane & 15;     // batch row within tile / MFMA col
    const int g    = lane >> 4;     // lane group 0..3 (k-slice / D-row group)
    unsigned char* h1hi = smem + wv * 8192;             // [16 rows][128 feats] f16, 256B rows
    unsigned char* h1lo = h1hi + 4096;
    const unsigned swz = ((unsigned)(r16 & 7)) << 4;
    const int slot = blockIdx.x * 4 + wv;               // 0..2047

    // ---- one-time: build fc1 concat-A frags in LDS (threads 0-127: one row each) ----
    if (tid < 128) {
        float v[8];
#pragma unroll
        for (int j = 0; j < 5; ++j) v[j] = w1[tid * 5 + j];
        v[5] = b1[tid];                                 // bias as K-column 5
        v[6] = 0.f; v[7] = 0.f;
        half8 hi, lo;
        split8(v, hi, lo);
        *(half8*)(smem + 32768 + tid * 16) = hi;
        *(half8*)(smem + 34816 + tid * 16) = lo;
    }
    if (tid == 128) {
        half8 z = {0,0,0,0,0,0,0,0};
        *(half8*)(smem + 36864) = z;
    }

    // ---- one-time: gather w2cat fragments into registers (128 VGPR, pinned) ----
    // frag lane l holds A[row=l&15][k=(l>>4)*8+j]; tile t covers w2cat rows 16t..16t+15
    half8 w2h[4][4], w2l[4][4];
#pragma unroll
    for (int t = 0; t < 4; ++t) {
        const int r = 16 * t + r16;
        const float* src = (r < 32) ? (w21 + r * 128) : (w22 + (r - 32) * 128);
#pragma unroll
        for (int kc = 0; kc < 4; ++kc) {
            const float4 f0 = *(const float4*)(src + kc * 32 + g * 8);
            const float4 f1 = *(const float4*)(src + kc * 32 + g * 8 + 4);
            float v[8];
            v[0] = f0.x; v[1] = f0.y; v[2] = f0.z; v[3] = f0.w;
            v[4] = f1.x; v[5] = f1.y; v[6] = f1.z; v[7] = f1.w;
            split8(v, w2h[t][kc], w2l[t][kc]);
            pin(w2h[t][kc]);
            pin(w2l[t][kc]);
        }
    }

    __syncthreads();    // w1c LDS ready; only barrier in the kernel

    // hoisted uniform scalars (SGPR)
    const float m0 = mean_[0], m1 = mean_[1], m2 = mean_[2], m3 = mean_[3];
    const float sd0 = std_[0], sd1 = std_[1], sd2 = std_[2], sd3 = std_[3];
    const float bb31_0 = b31[0], bb31_1 = b31[1], bb32_0 = b32[0], bb32_1 = b32[1];

    // fc1 A-frag LDS byte offset for this lane (g<2: hi row, g==2: lo row, g==3: zeros)
    const unsigned awbase = (g < 2) ? 32768u : ((g == 2) ? 34816u : 36864u);
    const unsigned awstep = (g == 3) ? 0u : 16u;        // zero row is not indexed by fr

    // ---- x prefetch for tile 0 (all lanes load row r16: quad-broadcast) ----
    float xa0, xa1, xa2, xa3, xa4;
    {
        const float* xr = x + (size_t)(slot * TPW * 16 + r16) * 5;
        xa0 = xr[0]; xa1 = xr[1]; xa2 = xr[2]; xa3 = xr[3]; xa4 = xr[4];
    }

#pragma unroll 1
    for (int it = 0; it < TPW; ++it) {
        const int rowbase = (slot * TPW + it) * 16;

        // ---- build fc1 concat B-frag: [xh(5),1 | xl(5),0 | xh(5),1 | 0] over k-groups ----
        half8 bx = {0,0,0,0,0,0,0,0};
        {
            float xs[5] = {xa0, xa1, xa2, xa3, xa4};
            const bool useL = (g == 1), useZ = (g == 3);
#pragma unroll
            for (int j = 0; j < 5; ++j) {
                _Float16 h = (_Float16)xs[j];
                _Float16 l = (_Float16)(xs[j] - (float)h);
                bx[j] = useZ ? (_Float16)0.f : (useL ? l : h);
            }
            bx[5] = (useZ || useL) ? (_Float16)0.f : (_Float16)1.0f;
        }
        const float xc0 = xa0, xc1 = xa1, xc2 = xa2, xc3 = xa3;  // for epilogue

        // prefetch next tile's x (latency hides under fc1/fc2)
        if (it + 1 < TPW) {
            const float* xr = x + (size_t)(rowbase + 16 + r16) * 5;
            xa0 = xr[0]; xa1 = xr[1]; xa2 = xr[2]; xa3 = xr[3]; xa4 = xr[4];
        }

        // ---- fc1 = relu(W1'[x;1]^T): ONE MFMA per 16-feat block (3 split terms in K) ----
#pragma unroll
        for (int t8 = 0; t8 < 8; ++t8) {
            const int fr = t8 * 16 + r16;
            const half8 aw = *(const half8*)(smem + awbase + (unsigned)fr * awstep);
            f32x4 acc = {0.f, 0.f, 0.f, 0.f};
            acc = __builtin_amdgcn_mfma_f32_16x16x32_f16(aw, bx, acc, 0, 0, 0);
            float v0 = fmaxf(acc[0], 0.f), v1 = fmaxf(acc[1], 0.f);
            float v2 = fmaxf(acc[2], 0.f), v3 = fmaxf(acc[3], 0.f);
            half2v hA = pkrtz(v0, v1);
            half2v hB = pkrtz(v2, v3);
            half2v lA = pkrtz(v0 - (float)hA[0], v1 - (float)hA[1]);
            half2v lB = pkrtz(v2 - (float)hB[0], v3 - (float)hB[1]);
            const unsigned off = ((unsigned)(32 * t8 + 8 * g)) ^ swz;
            uint2 ph; ph.x = __builtin_bit_cast(unsigned, hA); ph.y = __builtin_bit_cast(unsigned, hB);
            uint2 pl; pl.x = __builtin_bit_cast(unsigned, lA); pl.y = __builtin_bit_cast(unsigned, lB);
            *(uint2*)(h1hi + r16 * 256 + off) = ph;
            *(uint2*)(h1lo + r16 * 256 + off) = pl;
        }

        asm volatile("" ::: "memory");   // forbid IR reorder of LDS write->read across type-puns

        // ---- fc2cat: D[out 16t+4g+r][batch r16] = W2cat(A,reg) @ h1(B,LDS), fp16x3 ----
        half8 ah[4], al[4];
#pragma unroll
        for (int kc = 0; kc < 4; ++kc) {
            const unsigned off = ((unsigned)(kc * 64 + g * 16)) ^ swz;
            ah[kc] = *(const half8*)(h1hi + r16 * 256 + off);
            al[kc] = *(const half8*)(h1lo + r16 * 256 + off);
        }
        f32x4 acc2[4];
#pragma unroll
        for (int t = 0; t < 4; ++t) {
            const float4 bb2 = (t < 2) ? *(const float4*)(b21 + 16 * t + 4 * g)
                                       : *(const float4*)(b22 + 16 * (t - 2) + 4 * g);
            f32x4 a = {bb2.x, bb2.y, bb2.z, bb2.w};
#pragma unroll
            for (int kc = 0; kc < 4; ++kc) {
                a = __builtin_amdgcn_mfma_f32_16x16x32_f16(w2h[t][kc], al[kc], a, 0, 0, 0);
                a = __builtin_amdgcn_mfma_f32_16x16x32_f16(w2l[t][kc], ah[kc], a, 0, 0, 0);
                a = __builtin_amdgcn_mfma_f32_16x16x32_f16(w2h[t][kc], ah[kc], a, 0, 0, 0);
            }
            acc2[t] = a;
        }

        asm volatile("" ::: "memory");   // forbid next-iter LDS writes moving above these reads

        // ---- heads: per-lane partials over outs {16t+4g+r}, reduce over g (2 shfls) ----
        const f32x4 wA0 = *(const f32x4*)(w31 + 4 * g);       // x31 row0, x21 inputs 0-15
        const f32x4 wA1 = *(const f32x4*)(w31 + 16 + 4 * g);  //           x21 inputs 16-31
        const f32x4 wB0 = *(const f32x4*)(w31 + 32 + 4 * g);  // x31 row1
        const f32x4 wB1 = *(const f32x4*)(w31 + 48 + 4 * g);
        const f32x4 wC0 = *(const f32x4*)(w32 + 4 * g);       // x32 row0
        const f32x4 wC1 = *(const f32x4*)(w32 + 16 + 4 * g);
        const f32x4 wD0 = *(const f32x4*)(w32 + 32 + 4 * g);  // x32 row1
        const f32x4 wD1 = *(const f32x4*)(w32 + 48 + 4 * g);
        float p0 = 0.f, p1 = 0.f, p2 = 0.f, p3 = 0.f;
#pragma unroll
        for (int r = 0; r < 4; ++r) {
            float v0 = fmaxf(acc2[0][r], 0.f), v1 = fmaxf(acc2[1][r], 0.f);
            float v2 = fmaxf(acc2[2][r], 0.f), v3 = fmaxf(acc2[3][r], 0.f);
            p0 += wA0[r] * v0 + wA1[r] * v1;
            p1 += wB0[r] * v0 + wB1[r] * v1;
            p2 += wC0[r] * v2 + wC1[r] * v3;
            p3 += wD0[r] * v2 + wD1[r] * v3;
        }
        p0 += __shfl_xor(p0, 16); p0 += __shfl_xor(p0, 32);
        p1 += __shfl_xor(p1, 16); p1 += __shfl_xor(p1, 32);
        p2 += __shfl_xor(p2, 16); p2 += __shfl_xor(p2, 32);
        p3 += __shfl_xor(p3, 16); p3 += __shfl_xor(p3, 32);

        // ---- physics epilogue on lanes 0-15 (batch = r16) ----
        if (lane < 16) {
            const float a31_0 = p0 + bb31_0, a31_1 = p1 + bb31_1;
            const float a32_0 = p2 + bb32_0, a32_1 = p3 + bb32_1;
            const float s0 = 4.0f / (1.0f + __expf(-a32_0));
            const float s1 = 4.0f / (1.0f + __expf(-a32_1));
            const float px = fmaf(xc0, sd0, m0);
            const float py = fmaf(xc1, sd1, m1);
            const float th = fmaf(xc2, sd2, m2);
            const float v  = fmaf(xc3, sd3, m3);
            float sn, cs; __sincosf(th, &sn, &cs);
            const float dx = px - OBS_X, dy = py - OBS_Y;
            const float barrier     = dx * dx + dy * dy - RADIUS * RADIUS;
            const float barrier_dot = 2.f * dx * v * cs + 2.f * dy * v * sn;
            const float Lf2b = 2.f * v * v;
            const float G0 = 2.f * dx * v * sn - 2.f * dy * v * cs;   // -LgLfbu1
            const float G1 = -(2.f * dx * cs + 2.f * dy * sn);        // -LgLfbu2
            const float h  = Lf2b + (s0 + s1) * barrier_dot + s0 * s1 * barrier;
            const float u00 = -a31_0, u01 = -a31_1;
            const float viol = G0 * u00 + G1 * u01 - h;
            const float gg   = G0 * G0 + G1 * G1;
            const float lam  = fmaxf(viol, 0.f) / (gg + 1e-12f);
            float2 uo = make_float2(fmaf(-lam, G0, u00), fmaf(-lam, G1, u01));
            ((float2*)out)[rowbase + r16] = uo;
        }
    }
}

extern "C" void kernel_launch(void* const* d_in, const int* in_sizes, int n_in,
                              void* d_out, int out_size, void* d_ws, size_t ws_size,
                              hipStream_t stream) {
    const float* x     = (const float*)d_in[0];
    // d_in[1] = sgn (unused by the reference computation)
    const float* mean_ = (const float*)d_in[2];
    const float* std_  = (const float*)d_in[3];
    const float* w1    = (const float*)d_in[4];
    const float* b1    = (const float*)d_in[5];
    const float* w21   = (const float*)d_in[6];
    const float* b21   = (const float*)d_in[7];
    const float* w22   = (const float*)d_in[8];
    const float* b22   = (const float*)d_in[9];
    const float* w31   = (const float*)d_in[10];
    const float* b31   = (const float*)d_in[11];
    const float* w32   = (const float*)d_in[12];
    const float* b32   = (const float*)d_in[13];

    barriernet_fused<<<GRID, 256, 0, stream>>>(
        x, mean_, std_, w1, b1, w21, b21, w22, b22, w31, b31, w32, b32,
        (float*)d_out);
}